// Round 4
// baseline (198.643 us; speedup 1.0000x reference)
//
#include <hip/hip_runtime.h>
#include <hip/hip_bf16.h>
#include <math.h>

#define NCLS 256
#define PER_CLASS 128
#define NSUP 5
#define NQRY 123              // PER_CLASS - NSUP
#define NVIEW 2
#define DD 384
#define NQ_TOT (NCLS * NQRY)  // 31488
#define BM 128                // queries per block
#define BK 64                 // k-tile (elems)
#define RSTR 72               // LDS row stride in ushorts (64 data + 8 pad = 144 B; 16B-aligned, 2-way-max banks)

typedef __attribute__((ext_vector_type(8))) short short8;
typedef __attribute__((ext_vector_type(4))) float floatx4;

union FragU { uint4 u; short8 s; };
union PkU { __hip_bfloat162 b2; unsigned int u; };

__device__ __forceinline__ unsigned int cvt2bf(float lo, float hi) {
    PkU p;
    p.b2 = __float22bfloat162_rn(make_float2(lo, hi));
    return p.u;
}

// ---------- kernel 1: prototypes -> bf16 + y2, fused ----------
__global__ __launch_bounds__(384) void proto_kernel(const float* __restrict__ reps,
                                                    ushort* __restrict__ pbf,
                                                    float* __restrict__ y2) {
    __shared__ float wp[6];
    const int b = blockIdx.x;          // v*256 + c
    const int c = b & 255, v = b >> 8;
    const int d = threadIdx.x;         // 0..383
    const float* p = reps + ((size_t)(c * PER_CLASS) * NVIEW + v) * DD + d;
    float s = 0.f;
#pragma unroll
    for (int k = 0; k < NSUP; ++k) s += p[(size_t)k * NVIEW * DD];
    s *= 0.2f;
    __hip_bfloat16 h = __float2bfloat16(s);
    pbf[(size_t)b * DD + d] = *reinterpret_cast<ushort*>(&h);
    float q = s * s;
#pragma unroll
    for (int o = 1; o < 64; o <<= 1) q += __shfl_xor(q, o);
    if ((d & 63) == 0) wp[d >> 6] = q;
    __syncthreads();
    if (d == 0) y2[b] = wp[0] + wp[1] + wp[2] + wp[3] + wp[4] + wp[5];
}

// ---------- kernel 2: bf16 MFMA GEMM (128q x 256c, K=384, BK=64) + fused logsumexp/NLL ----------
__global__ __launch_bounds__(256, 2) void main_kernel(const float* __restrict__ reps,
                                                      const ushort* __restrict__ pbf,
                                                      const float* __restrict__ y2g,
                                                      float* __restrict__ out) {
    __shared__ ushort q_lds[BM * RSTR];    // 18432 B
    __shared__ ushort p_lds[NCLS * RSTR];  // 36864 B
    __shared__ float pmx[BM][2];
    __shared__ float pse[BM][2];
    __shared__ float wred[8];

    const int t = threadIdx.x;
    const int v = blockIdx.y;
    const int q0 = blockIdx.x * BM;
    const int wave = t >> 6;
    const int lane = t & 63;
    const int col = lane & 15;   // MFMA m/n index
    const int quad = lane >> 4;  // MFMA k-chunk / C row group
    const int wm = wave >> 1;    // query half  (rows 0-63 / 64-127)
    const int wn = wave & 1;     // class half  (cols 0-127 / 128-255)

    // staging: Q: 2 threads/row (t>>1 = row, (t&1)*32 = float col); P: 1 thread/row (128 B)
    const int sq = t >> 1;
    const int h = (t & 1) * 32;
    const int nq = q0 + sq;
    const float* qsrc = reps +
        (size_t)((nq / NQRY) * PER_CLASS + NSUP + (nq % NQRY)) * (NVIEW * DD) + v * DD + h;
    const ushort* psrc = pbf + (size_t)(v * NCLS + t) * DD;
    ushort* qdst = &q_lds[sq * RSTR + h];
    ushort* pdst = &p_lds[t * RSTR];

    floatx4 acc[4][8];
#pragma unroll
    for (int mt = 0; mt < 4; ++mt)
#pragma unroll
        for (int nt = 0; nt < 8; ++nt) acc[mt][nt] = (floatx4)0.f;

    for (int kt = 0; kt < DD / BK; ++kt) {
        // prefetch into VGPRs (overlaps other waves' MFMA + the barrier)
        float4 qf[8];
        uint4 pl[8];
#pragma unroll
        for (int i = 0; i < 8; ++i) qf[i] = *(const float4*)(qsrc + kt * BK + i * 4);
#pragma unroll
        for (int i = 0; i < 8; ++i) pl[i] = ((const uint4*)(psrc + kt * BK))[i];
        // convert Q to bf16 while loads/compute drain
        uint4 qw[4];
#pragma unroll
        for (int i = 0; i < 4; ++i) {
            qw[i].x = cvt2bf(qf[2 * i].x, qf[2 * i].y);
            qw[i].y = cvt2bf(qf[2 * i].z, qf[2 * i].w);
            qw[i].z = cvt2bf(qf[2 * i + 1].x, qf[2 * i + 1].y);
            qw[i].w = cvt2bf(qf[2 * i + 1].z, qf[2 * i + 1].w);
        }

        if (kt) __syncthreads();  // prior tile's frag reads complete before overwrite
#pragma unroll
        for (int i = 0; i < 4; ++i) *(uint4*)(qdst + h * 0 + i * 8) = qw[i];
#pragma unroll
        for (int i = 0; i < 8; ++i) *(uint4*)(pdst + i * 8) = pl[i];
        __syncthreads();

#pragma unroll
        for (int ks = 0; ks < 2; ++ks) {
            short8 af[4];
#pragma unroll
            for (int mt = 0; mt < 4; ++mt) {
                FragU f;
                f.u = *(const uint4*)&q_lds[(wm * 64 + mt * 16 + col) * RSTR + ks * 32 + quad * 8];
                af[mt] = f.s;
            }
#pragma unroll
            for (int nt = 0; nt < 8; ++nt) {
                FragU b;
                b.u = *(const uint4*)&p_lds[(wn * 128 + nt * 16 + col) * RSTR + ks * 32 + quad * 8];
#pragma unroll
                for (int mt = 0; mt < 4; ++mt)
                    acc[mt][nt] = __builtin_amdgcn_mfma_f32_16x16x32_bf16(af[mt], b.s, acc[mt][nt], 0, 0, 0);
            }
        }
    }

    // ---- epilogue (identical to verified r2) ----
    float y2c[8];
#pragma unroll
    for (int nt = 0; nt < 8; ++nt) y2c[nt] = y2g[v * NCLS + wn * 128 + nt * 16 + col];

    float corr = 0.f;
#pragma unroll
    for (int mt = 0; mt < 4; ++mt) {
#pragma unroll
        for (int r = 0; r < 4; ++r) {
            const int qloc = wm * 64 + mt * 16 + quad * 4 + r;
            const int n = q0 + qloc;
            const int cn = n / NQRY;
            float s[8];
            float mx = -1e30f;
#pragma unroll
            for (int nt = 0; nt < 8; ++nt) {
                s[nt] = 2.f * acc[mt][nt][r] - y2c[nt];
                mx = fmaxf(mx, s[nt]);
                if (cn == wn * 128 + nt * 16 + col) corr += s[nt];
            }
#pragma unroll
            for (int o = 1; o < 16; o <<= 1) mx = fmaxf(mx, __shfl_xor(mx, o));
            float e = 0.f;
#pragma unroll
            for (int nt = 0; nt < 8; ++nt) e += __expf(s[nt] - mx);
#pragma unroll
            for (int o = 1; o < 16; o <<= 1) e += __shfl_xor(e, o);
            if (col == 0) { pmx[qloc][wn] = mx; pse[qloc][wn] = e; }
        }
    }
#pragma unroll
    for (int o = 1; o < 64; o <<= 1) corr += __shfl_xor(corr, o);
    if (lane == 0) wred[wave] = corr;
    __syncthreads();

    float lval = 0.f;
    if (t < BM) {
        float m0 = pmx[t][0], m1 = pmx[t][1];
        float M = fmaxf(m0, m1);
        float E = pse[t][0] * __expf(m0 - M) + pse[t][1] * __expf(m1 - M);
        lval = M + __logf(E);
    }
#pragma unroll
    for (int o = 1; o < 64; o <<= 1) lval += __shfl_xor(lval, o);
    if (lane == 0) wred[4 + wave] = lval;
    __syncthreads();

    if (t == 0) {
        float tot = (wred[4] + wred[5] + wred[6] + wred[7]) -
                    (wred[0] + wred[1] + wred[2] + wred[3]);
        atomicAdd(out, tot * (1.f / (float)(NQ_TOT * NVIEW)));
    }
}

extern "C" void kernel_launch(void* const* d_in, const int* in_sizes, int n_in,
                              void* d_out, int out_size, void* d_ws, size_t ws_size,
                              hipStream_t stream) {
    const float* reps = (const float*)d_in[0];
    float* ws = (float*)d_ws;
    ushort* pbf = (ushort*)ws;                          // 196608 ushorts
    float* y2 = (float*)(pbf + NVIEW * NCLS * DD);      // 512 floats
    float* out = (float*)d_out;

    hipMemsetAsync(out, 0, sizeof(float), stream);
    proto_kernel<<<dim3(NVIEW * NCLS), dim3(DD), 0, stream>>>(reps, pbf, y2);
    main_kernel<<<dim3(NQ_TOT / BM, NVIEW), dim3(256), 0, stream>>>(reps, pbf, y2, out);
}

// Round 5
// 166.434 us; speedup vs baseline: 1.1935x; 1.1935x over previous
//
#include <hip/hip_runtime.h>
#include <hip/hip_bf16.h>
#include <math.h>

#define NCLS 256
#define PER_CLASS 128
#define NSUP 5
#define NQRY 123              // PER_CLASS - NSUP
#define NVIEW 2
#define DD 384
#define NQ_TOT (NCLS * NQRY)  // 31488
#define BM 128                // queries per block
#define BK 64                 // k-tile (elems)
#define NKT (DD / BK)         // 6 k-tiles
#define RSTR 72               // Q LDS row stride in ushorts (64 data + 8 pad; 2-way-max banks)
#define PTILE (NCLS * BK)     // ushorts per packed P k-tile (16384 = 32 KB)

typedef __attribute__((ext_vector_type(8))) short short8;
typedef __attribute__((ext_vector_type(4))) float floatx4;

union FragU { uint4 u; short8 s; };
union PkU { __hip_bfloat162 b2; unsigned int u; };

__device__ __forceinline__ unsigned int cvt2bf(float lo, float hi) {
    PkU p;
    p.b2 = __float22bfloat162_rn(make_float2(lo, hi));
    return p.u;
}

// async global->LDS, 16 B per lane; LDS dest wave-uniform base + lane*16
__device__ __forceinline__ void load16(const void* g, void* l) {
    __builtin_amdgcn_global_load_lds(
        (const __attribute__((address_space(1))) unsigned int*)g,
        (__attribute__((address_space(3))) unsigned int*)l, 16, 0, 0);
}

// ---------- kernel 1: prototypes -> packed-swizzled bf16 P image + y2 ----------
// Packed layout: [v][kt][row=c][slot(8)][8 ushorts], slot = chunk ^ (c & 7).
// This is byte-identical to the main kernel's desired LDS image per k-tile.
__global__ __launch_bounds__(384) void proto_kernel(const float* __restrict__ reps,
                                                    ushort* __restrict__ ppk,
                                                    float* __restrict__ y2) {
    __shared__ float wp[6];
    const int b = blockIdx.x;          // v*256 + c
    const int c = b & 255, v = b >> 8;
    const int d = threadIdx.x;         // 0..383
    const float* p = reps + ((size_t)(c * PER_CLASS) * NVIEW + v) * DD + d;
    float s = 0.f;
#pragma unroll
    for (int k = 0; k < NSUP; ++k) s += p[(size_t)k * NVIEW * DD];
    s *= 0.2f;
    __hip_bfloat16 hh = __float2bfloat16(s);
    const int kt = d >> 6;             // k-tile
    const int ch = (d >> 3) & 7;       // 16B chunk within row
    const int w = d & 7;               // ushort within chunk
    const int slot = ch ^ (c & 7);
    ppk[((size_t)(v * NKT + kt) * NCLS + c) * BK + slot * 8 + w] =
        *reinterpret_cast<ushort*>(&hh);
    float q = s * s;
#pragma unroll
    for (int o = 1; o < 64; o <<= 1) q += __shfl_xor(q, o);
    if ((d & 63) == 0) wp[d >> 6] = q;
    __syncthreads();
    if (d == 0) y2[b] = wp[0] + wp[1] + wp[2] + wp[3] + wp[4] + wp[5];
}

// ---------- kernel 2: bf16 MFMA GEMM (128q x 256c, K=384, BK=64) + fused logsumexp/NLL ----------
__global__ __launch_bounds__(256, 2) void main_kernel(const float* __restrict__ reps,
                                                      const ushort* __restrict__ ppk,
                                                      const float* __restrict__ y2g,
                                                      float* __restrict__ out) {
    __shared__ ushort q_lds[BM * RSTR];   // 18432 B (padded, VGPR-path staging)
    __shared__ ushort p_lds[PTILE];       // 32768 B (unpadded, global_load_lds image)
    __shared__ float pmx[BM][2];
    __shared__ float pse[BM][2];
    __shared__ float wred[8];

    const int t = threadIdx.x;
    const int v = blockIdx.y;
    const int q0 = blockIdx.x * BM;
    const int wave = t >> 6;
    const int lane = t & 63;
    const int col = lane & 15;   // MFMA m/n index
    const int quad = lane >> 4;  // MFMA k-chunk / C row group
    const int wm = wave >> 1;    // query half
    const int wn = wave & 1;     // class half

    // Q staging: 2 threads/row; t>>1 = row, (t&1)*32 = element offset
    const int sq = t >> 1;
    const int h = (t & 1) * 32;
    const int nq = q0 + sq;
    const float* qsrc = reps +
        (size_t)((nq / NQRY) * PER_CLASS + NSUP + (nq % NQRY)) * (NVIEW * DD) + v * DD + h;
    ushort* qdst = &q_lds[sq * RSTR + h];
    // P staging: 8 contiguous 1KB global_load_lds per wave per k-tile
    const ushort* psrc = ppk + (size_t)v * NKT * PTILE + (wave * 8) * 512 + lane * 8;
    ushort* pdst0 = &p_lds[(wave * 8) * 512];

    floatx4 acc[4][8];
#pragma unroll
    for (int mt = 0; mt < 4; ++mt)
#pragma unroll
        for (int nt = 0; nt < 8; ++nt) acc[mt][nt] = (floatx4)0.f;

    for (int kt = 0; kt < NKT; ++kt) {
        // Q prefetch into VGPRs + convert (all dead before the barrier)
        float4 qf[8];
#pragma unroll
        for (int i = 0; i < 8; ++i) qf[i] = *(const float4*)(qsrc + kt * BK + i * 4);
        uint4 qw[4];
#pragma unroll
        for (int i = 0; i < 4; ++i) {
            qw[i].x = cvt2bf(qf[2 * i].x, qf[2 * i].y);
            qw[i].y = cvt2bf(qf[2 * i].z, qf[2 * i].w);
            qw[i].z = cvt2bf(qf[2 * i + 1].x, qf[2 * i + 1].y);
            qw[i].w = cvt2bf(qf[2 * i + 1].z, qf[2 * i + 1].w);
        }

        if (kt) __syncthreads();  // prior tile's frag reads complete
        // P: async DMA, contiguous 1 KB per instruction
#pragma unroll
        for (int i = 0; i < 8; ++i)
            load16(psrc + (size_t)kt * PTILE + i * 512, pdst0 + i * 512);
        // Q: VGPR -> LDS
#pragma unroll
        for (int i = 0; i < 4; ++i) *(uint4*)(qdst + i * 8) = qw[i];
        __syncthreads();  // drains vmcnt (async P) + lgkm (Q writes)

#pragma unroll
        for (int ks = 0; ks < 2; ++ks) {
            short8 af[4];
#pragma unroll
            for (int mt = 0; mt < 4; ++mt) {
                FragU f;
                f.u = *(const uint4*)&q_lds[(wm * 64 + mt * 16 + col) * RSTR + ks * 32 + quad * 8];
                af[mt] = f.s;
            }
#pragma unroll
            for (int nt = 0; nt < 8; ++nt) {
                FragU b;
                // swizzled slot: chunk (4ks+quad) of row (wn*128+nt*16+col)
                b.u = *(const uint4*)&p_lds[(wn * 128 + nt * 16 + col) * BK +
                                            ((4 * ks + quad) ^ (col & 7)) * 8];
#pragma unroll
                for (int mt = 0; mt < 4; ++mt)
                    acc[mt][nt] = __builtin_amdgcn_mfma_f32_16x16x32_bf16(af[mt], b.s, acc[mt][nt], 0, 0, 0);
            }
        }
    }

    // ---- epilogue (identical to verified r2) ----
    float y2c[8];
#pragma unroll
    for (int nt = 0; nt < 8; ++nt) y2c[nt] = y2g[v * NCLS + wn * 128 + nt * 16 + col];

    float corr = 0.f;
#pragma unroll
    for (int mt = 0; mt < 4; ++mt) {
#pragma unroll
        for (int r = 0; r < 4; ++r) {
            const int qloc = wm * 64 + mt * 16 + quad * 4 + r;
            const int n = q0 + qloc;
            const int cn = n / NQRY;
            float s[8];
            float mx = -1e30f;
#pragma unroll
            for (int nt = 0; nt < 8; ++nt) {
                s[nt] = 2.f * acc[mt][nt][r] - y2c[nt];
                mx = fmaxf(mx, s[nt]);
                if (cn == wn * 128 + nt * 16 + col) corr += s[nt];
            }
#pragma unroll
            for (int o = 1; o < 16; o <<= 1) mx = fmaxf(mx, __shfl_xor(mx, o));
            float e = 0.f;
#pragma unroll
            for (int nt = 0; nt < 8; ++nt) e += __expf(s[nt] - mx);
#pragma unroll
            for (int o = 1; o < 16; o <<= 1) e += __shfl_xor(e, o);
            if (col == 0) { pmx[qloc][wn] = mx; pse[qloc][wn] = e; }
        }
    }
#pragma unroll
    for (int o = 1; o < 64; o <<= 1) corr += __shfl_xor(corr, o);
    if (lane == 0) wred[wave] = corr;
    __syncthreads();

    float lval = 0.f;
    if (t < BM) {
        float m0 = pmx[t][0], m1 = pmx[t][1];
        float M = fmaxf(m0, m1);
        float E = pse[t][0] * __expf(m0 - M) + pse[t][1] * __expf(m1 - M);
        lval = M + __logf(E);
    }
#pragma unroll
    for (int o = 1; o < 64; o <<= 1) lval += __shfl_xor(lval, o);
    if (lane == 0) wred[4 + wave] = lval;
    __syncthreads();

    if (t == 0) {
        float tot = (wred[4] + wred[5] + wred[6] + wred[7]) -
                    (wred[0] + wred[1] + wred[2] + wred[3]);
        atomicAdd(out, tot * (1.f / (float)(NQ_TOT * NVIEW)));
    }
}

extern "C" void kernel_launch(void* const* d_in, const int* in_sizes, int n_in,
                              void* d_out, int out_size, void* d_ws, size_t ws_size,
                              hipStream_t stream) {
    const float* reps = (const float*)d_in[0];
    float* ws = (float*)d_ws;
    ushort* ppk = (ushort*)ws;                       // 2*6*16384 = 196608 ushorts
    float* y2 = (float*)(ppk + NVIEW * NKT * PTILE); // 512 floats
    float* out = (float*)d_out;

    hipMemsetAsync(out, 0, sizeof(float), stream);
    proto_kernel<<<dim3(NVIEW * NCLS), dim3(DD), 0, stream>>>(reps, ppk, y2);
    main_kernel<<<dim3(NQ_TOT / BM, NVIEW), dim3(256), 0, stream>>>(reps, ppk, y2, out);
}

// Round 6
// 165.990 us; speedup vs baseline: 1.1967x; 1.0027x over previous
//
#include <hip/hip_runtime.h>
#include <hip/hip_bf16.h>
#include <math.h>

#define NCLS 256
#define PER_CLASS 128
#define NSUP 5
#define NQRY 123              // PER_CLASS - NSUP
#define NVIEW 2
#define DD 384
#define NQ_TOT (NCLS * NQRY)  // 31488
#define BM 128                // queries per block
#define BK 32                 // k-tile (elems)
#define NKT (DD / BK)         // 12
#define QS 40                 // LDS row stride in ushorts (32 data + 8 pad; 16B-aligned, 2-way-max banks)

typedef __attribute__((ext_vector_type(8))) short short8;
typedef __attribute__((ext_vector_type(4))) float floatx4;

union FragU { uint4 u; short8 s; };
union PkU { __hip_bfloat162 b2; unsigned int u; };

__device__ __forceinline__ unsigned int cvt2bf(float lo, float hi) {
    PkU p;
    p.b2 = __float22bfloat162_rn(make_float2(lo, hi));
    return p.u;
}

// barrier WITHOUT the vmcnt(0) drain __syncthreads would emit:
// LDS writes must be visible (lgkmcnt(0)), but in-flight global loads keep flying.
#define BARRIER() asm volatile("s_waitcnt lgkmcnt(0)\n\ts_barrier" ::: "memory")

// ---------- kernel 1: prototypes -> bf16 + y2, fused ----------
__global__ __launch_bounds__(384) void proto_kernel(const float* __restrict__ reps,
                                                    ushort* __restrict__ pbf,
                                                    float* __restrict__ y2) {
    __shared__ float wp[6];
    const int b = blockIdx.x;          // v*256 + c
    const int c = b & 255, v = b >> 8;
    const int d = threadIdx.x;         // 0..383
    const float* p = reps + ((size_t)(c * PER_CLASS) * NVIEW + v) * DD + d;
    float s = 0.f;
#pragma unroll
    for (int k = 0; k < NSUP; ++k) s += p[(size_t)k * NVIEW * DD];
    s *= 0.2f;
    __hip_bfloat16 h = __float2bfloat16(s);
    pbf[(size_t)b * DD + d] = *reinterpret_cast<ushort*>(&h);
    float q = s * s;
#pragma unroll
    for (int o = 1; o < 64; o <<= 1) q += __shfl_xor(q, o);
    if ((d & 63) == 0) wp[d >> 6] = q;
    __syncthreads();
    if (d == 0) y2[b] = wp[0] + wp[1] + wp[2] + wp[3] + wp[4] + wp[5];
}

// ---------- kernel 2: software-pipelined bf16 MFMA GEMM + fused logsumexp/NLL ----------
__global__ __launch_bounds__(256, 2) void main_kernel(const float* __restrict__ reps,
                                                      const ushort* __restrict__ pbf,
                                                      const float* __restrict__ y2g,
                                                      float* __restrict__ out) {
    __shared__ ushort q_lds[2][BM * QS];    // 2 x 10240 B
    __shared__ ushort p_lds[2][NCLS * QS];  // 2 x 20480 B
    __shared__ float pmx[BM][2];
    __shared__ float pse[BM][2];
    __shared__ float wred[8];

    const int t = threadIdx.x;
    const int v = blockIdx.y;
    const int q0 = blockIdx.x * BM;
    const int wave = t >> 6;
    const int lane = t & 63;
    const int col = lane & 15;   // MFMA m/n index
    const int quad = lane >> 4;  // MFMA k-chunk / C row group
    const int wm = wave >> 1;    // query half
    const int wn = wave & 1;     // class half

    // staging maps: Q: 2 threads/row (t>>1 = row, (t&1)*16 = element offset); P: 1 thread/row
    const int sq = t >> 1;
    const int h16 = (t & 1) * 16;
    const int nq = q0 + sq;
    const float* qsrc = reps +
        (size_t)((nq / NQRY) * PER_CLASS + NSUP + (nq % NQRY)) * (NVIEW * DD) + v * DD + h16;
    const ushort* psrc = pbf + (size_t)(v * NCLS + t) * DD;

    floatx4 acc[4][8];
#pragma unroll
    for (int mt = 0; mt < 4; ++mt)
#pragma unroll
        for (int nt = 0; nt < 8; ++nt) acc[mt][nt] = (floatx4)0.f;

    float4 qf[4];
    uint4 pl[4];

#define LOADT(kt)                                                                  \
    do {                                                                           \
        _Pragma("unroll") for (int i = 0; i < 4; ++i)                              \
            qf[i] = *(const float4*)(qsrc + (kt) * BK + i * 4);                    \
        _Pragma("unroll") for (int i = 0; i < 4; ++i)                              \
            pl[i] = *((const uint4*)(psrc + (kt) * BK) + i);                       \
    } while (0)

#define STAGE(b)                                                                   \
    do {                                                                           \
        uint4 qw0, qw1;                                                            \
        qw0.x = cvt2bf(qf[0].x, qf[0].y); qw0.y = cvt2bf(qf[0].z, qf[0].w);        \
        qw0.z = cvt2bf(qf[1].x, qf[1].y); qw0.w = cvt2bf(qf[1].z, qf[1].w);        \
        qw1.x = cvt2bf(qf[2].x, qf[2].y); qw1.y = cvt2bf(qf[2].z, qf[2].w);        \
        qw1.z = cvt2bf(qf[3].x, qf[3].y); qw1.w = cvt2bf(qf[3].z, qf[3].w);        \
        *(uint4*)&q_lds[b][sq * QS + h16] = qw0;                                   \
        *(uint4*)&q_lds[b][sq * QS + h16 + 8] = qw1;                               \
        _Pragma("unroll") for (int i = 0; i < 4; ++i)                              \
            *(uint4*)&p_lds[b][t * QS + i * 8] = pl[i];                            \
    } while (0)

#define COMPUTE(b)                                                                 \
    do {                                                                           \
        short8 af[4];                                                              \
        _Pragma("unroll") for (int mt = 0; mt < 4; ++mt) {                         \
            FragU f;                                                               \
            f.u = *(const uint4*)&q_lds[b][(wm * 64 + mt * 16 + col) * QS + quad * 8]; \
            af[mt] = f.s;                                                          \
        }                                                                          \
        _Pragma("unroll") for (int nt = 0; nt < 8; ++nt) {                         \
            FragU bb;                                                              \
            bb.u = *(const uint4*)&p_lds[b][(wn * 128 + nt * 16 + col) * QS + quad * 8]; \
            _Pragma("unroll") for (int mt = 0; mt < 4; ++mt)                       \
                acc[mt][nt] = __builtin_amdgcn_mfma_f32_16x16x32_bf16(af[mt], bb.s, acc[mt][nt], 0, 0, 0); \
        }                                                                          \
    } while (0)

    // ---- pipelined K-loop: loads for kt+2 in flight across barrier kt ----
    LOADT(0);
    STAGE(0);
    LOADT(1);
    BARRIER();
#pragma unroll
    for (int kt = 0; kt < NKT; ++kt) {
        COMPUTE(kt & 1);
        if (kt < NKT - 1) {
            STAGE((kt + 1) & 1);   // vmcnt wait for tile kt+1 lands here, after COMPUTE(kt)
            if (kt < NKT - 2) LOADT(kt + 2);
            BARRIER();
        }
    }

    // ---- epilogue (identical to verified r2) ----
    float y2c[8];
#pragma unroll
    for (int nt = 0; nt < 8; ++nt) y2c[nt] = y2g[v * NCLS + wn * 128 + nt * 16 + col];

    float corr = 0.f;
#pragma unroll
    for (int mt = 0; mt < 4; ++mt) {
#pragma unroll
        for (int r = 0; r < 4; ++r) {
            const int qloc = wm * 64 + mt * 16 + quad * 4 + r;
            const int n = q0 + qloc;
            const int cn = n / NQRY;
            float s[8];
            float mx = -1e30f;
#pragma unroll
            for (int nt = 0; nt < 8; ++nt) {
                s[nt] = 2.f * acc[mt][nt][r] - y2c[nt];
                mx = fmaxf(mx, s[nt]);
                if (cn == wn * 128 + nt * 16 + col) corr += s[nt];
            }
#pragma unroll
            for (int o = 1; o < 16; o <<= 1) mx = fmaxf(mx, __shfl_xor(mx, o));
            float e = 0.f;
#pragma unroll
            for (int nt = 0; nt < 8; ++nt) e += __expf(s[nt] - mx);
#pragma unroll
            for (int o = 1; o < 16; o <<= 1) e += __shfl_xor(e, o);
            if (col == 0) { pmx[qloc][wn] = mx; pse[qloc][wn] = e; }
        }
    }
#pragma unroll
    for (int o = 1; o < 64; o <<= 1) corr += __shfl_xor(corr, o);
    if (lane == 0) wred[wave] = corr;
    __syncthreads();

    float lval = 0.f;
    if (t < BM) {
        float m0 = pmx[t][0], m1 = pmx[t][1];
        float M = fmaxf(m0, m1);
        float E = pse[t][0] * __expf(m0 - M) + pse[t][1] * __expf(m1 - M);
        lval = M + __logf(E);
    }
#pragma unroll
    for (int o = 1; o < 64; o <<= 1) lval += __shfl_xor(lval, o);
    if (lane == 0) wred[4 + wave] = lval;
    __syncthreads();

    if (t == 0) {
        float tot = (wred[4] + wred[5] + wred[6] + wred[7]) -
                    (wred[0] + wred[1] + wred[2] + wred[3]);
        atomicAdd(out, tot * (1.f / (float)(NQ_TOT * NVIEW)));
    }
}

extern "C" void kernel_launch(void* const* d_in, const int* in_sizes, int n_in,
                              void* d_out, int out_size, void* d_ws, size_t ws_size,
                              hipStream_t stream) {
    const float* reps = (const float*)d_in[0];
    float* ws = (float*)d_ws;
    ushort* pbf = (ushort*)ws;                      // 196608 ushorts
    float* y2 = (float*)(pbf + NVIEW * NCLS * DD);  // 512 floats
    float* out = (float*)d_out;

    hipMemsetAsync(out, 0, sizeof(float), stream);
    proto_kernel<<<dim3(NVIEW * NCLS), dim3(DD), 0, stream>>>(reps, pbf, y2);
    main_kernel<<<dim3(NQ_TOT / BM, NVIEW), dim3(256), 0, stream>>>(reps, pbf, y2, out);
}